// Round 8
// baseline (135.521 us; speedup 1.0000x reference)
//
#include <hip/hip_runtime.h>

// Bilinear backward warp: img [B,C,H,W] f32, flo [B,2,H,W] f32 -> out [B,C,H,W] f32
// B=8, C=64, H=256, W=448
//
// R8 = R7 skeleton (4 rotating LDS buffers, 2 channels/round, one
// __syncthreads per round) with the rare out-of-band fallback REMOVED from the
// hot loop: clean path always reads clamped LDS offsets (garbage for ~0.3% of
// pixels), and a second fixup kernel recomputes those pixels from global.
// Rationale: dirty-wave masked global loads drained the stage prefetch (FIFO
// vmcnt) and the round barrier propagated that stall to the whole block ~74%
// of rounds.

#define BN 8
#define CN 64
#define HN 256
#define WN 448
#define HW (HN * WN)
#define R 4              // output rows per block
#define BAND 10          // staged img rows per channel (lo = h0-3)
#define TPB WN           // 448 threads = 7 waves
#define NXCD 8
#define CSPLIT 2
#define CLOOP (CN / CSPLIT)   // 32 channels per block
#define ROUNDS (CLOOP / 2)    // 16 rounds of 2 channels

typedef __attribute__((address_space(1))) const void glb_v;
typedef __attribute__((address_space(3))) void lds_v;

__global__ __launch_bounds__(TPB) void warp_kernel(const float* __restrict__ img,
                                                   const float* __restrict__ flo,
                                                   float* __restrict__ out) {
    // 4 buffers x (4480+4) floats = 71744 B -> 2 blocks/CU
    __shared__ float lds[4][BAND * WN + 4];

    // XCD swizzle: 1024 blocks = 128/XCD = one batch per XCD.
    const int nwg = gridDim.x;            // 1024
    const int cpx = nwg / NXCD;           // 128
    const int bid = blockIdx.x;
    const int wgid = (bid % NXCD) * cpx + (bid / NXCD);

    const int b    = wgid / cpx;          // 0..7
    const int rem  = wgid % cpx;          // 0..127
    const int tile = rem >> 1;            // 0..63
    const int ch0  = (rem & 1) * CLOOP;   // 0 or 32
    const int h0   = tile * R;
    const int w    = threadIdx.x;         // 0..447

    int lo = h0 - 3;
    lo = lo < 0 ? 0 : (lo > HN - BAND ? HN - BAND : lo);

    const float* imgb = img + (size_t)b * CN * HW;
    const float* flob = flo + (size_t)b * 2 * HW;

    // ---- per-pixel setup, channel-invariant (clean path only) ----
    float wa[R], wb[R], wc[R], wd[R];
    int sA[R], sB[R];       // band-relative LDS word offsets (row-clamped)
    int dx_[R];
#pragma unroll
    for (int r = 0; r < R; ++r) {
        const int h = h0 + r;
        const int hw = h * WN + w;
        const float fx = flob[hw];
        const float fy = flob[HW + hw];
        const float x = (float)w + fx;
        const float y = (float)h + fy;
        int x0 = (int)x;                 // trunc toward zero (matches ref)
        int x1 = x0 + 1;
        int y0 = (int)y;
        int y1 = y0 + 1;
        x0 = min(max(x0, 0), WN - 1);
        x1 = min(max(x1, 0), WN - 1);
        y0 = min(max(y0, 0), HN - 1);
        y1 = min(max(y1, 0), HN - 1);
        const float x0f = (float)x0, x1f = (float)x1;
        const float y0f = (float)y0, y1f = (float)y1;
        wa[r] = (x1f - x) * (y1f - y);
        wb[r] = (x1f - x) * (y - y0f);
        wc[r] = (x - x0f) * (y1f - y);
        wd[r] = (x - x0f) * (y - y0f);
        dx_[r] = x1 - x0;                // 0 only at l/r edge clip
        // clamp rows into band; out-of-band lanes produce garbage, fixed later
        const int rA = min(max(y0 - lo, 0), BAND - 1);
        const int rB = min(max(y1 - lo, 0), BAND - 1);
        sA[r] = rA * WN + x0;
        sB[r] = rB * WN + x0;
    }

    const int wave = threadIdx.x >> 6;   // 0..6
    const int lane = threadIdx.x & 63;

    // ---- staging: 10 rows x 448 = 4480 words = 17x1KB chunks + 2x256B tails ----
    auto stage = [&](int bufi, int c) {          // c = global channel
        const float* src = imgb + (size_t)c * HW + (size_t)lo * WN;
        float* dst = &lds[bufi][0];
        for (int s = wave; s < 17; s += 7) {
            __builtin_amdgcn_global_load_lds(
                (glb_v*)(src + s * 256 + lane * 4),
                (lds_v*)(dst + s * 256), 16, 0, 0);
        }
        if (wave < 2) {
            const int base = 17 * 256 + wave * 64;
            __builtin_amdgcn_global_load_lds(
                (glb_v*)(src + base + lane),
                (lds_v*)(dst + base), 4, 0, 0);
        }
    };

    stage(0, ch0 + 0);
    stage(1, ch0 + 1);
    __syncthreads();

    float* outp = out + (size_t)b * CN * HW + (size_t)ch0 * HW + (size_t)h0 * WN + w;

    for (int k = 0; k < ROUNDS; ++k) {
        const int m = 2 * k;                       // local channel of this round
        if (k + 1 < ROUNDS) {
            stage((m + 2) & 3, ch0 + m + 2);
            stage((m + 3) & 3, ch0 + m + 3);
        }

        const float* bufA = &lds[m & 3][0];
        const float* bufB = &lds[(m + 1) & 3][0];
        float oA[R], oB[R];
#pragma unroll
        for (int r = 0; r < R; ++r) {
            const float Aa0 = bufA[sA[r]];
            const float Aa1 = bufA[sA[r] + 1];   // ds_read2_b32 pair
            const float Ab0 = bufA[sB[r]];
            const float Ab1 = bufA[sB[r] + 1];
            const float Ba0 = bufB[sA[r]];
            const float Ba1 = bufB[sA[r] + 1];
            const float Bb0 = bufB[sB[r]];
            const float Bb1 = bufB[sB[r] + 1];
            const float AIc = dx_[r] ? Aa1 : Aa0;
            const float AId = dx_[r] ? Ab1 : Ab0;
            const float BIc = dx_[r] ? Ba1 : Ba0;
            const float BId = dx_[r] ? Bb1 : Bb0;
            oA[r] = wa[r] * Aa0 + wb[r] * Ab0 + wc[r] * AIc + wd[r] * AId;
            oB[r] = wa[r] * Ba0 + wb[r] * Bb0 + wc[r] * BIc + wd[r] * BId;
        }
#pragma unroll
        for (int r = 0; r < R; ++r) {
            outp[(size_t)m * HW + r * WN] = oA[r];
            outp[(size_t)(m + 1) * HW + r * WN] = oB[r];
        }
        __syncthreads();   // drain (stage k+1 landed) + barrier, once per 2 channels
    }
}

// Second pass: recompute the rare out-of-band pixels (all channels) from global.
__global__ __launch_bounds__(256) void fixup_kernel(const float* __restrict__ img,
                                                    const float* __restrict__ flo,
                                                    float* __restrict__ out) {
    int pix = blockIdx.x * blockDim.x + threadIdx.x;  // over B*H*W
    if (pix >= BN * HW) return;
    int b = pix / HW;
    int hw = pix - b * HW;
    int h = hw / WN;
    int w = hw - h * WN;

    const float fx = flo[(size_t)b * 2 * HW + hw];
    const float fy = flo[(size_t)b * 2 * HW + HW + hw];
    const float x = (float)w + fx;
    const float y = (float)h + fy;

    int x0 = (int)x;
    int x1 = x0 + 1;
    int y0 = (int)y;
    int y1 = y0 + 1;
    x0 = min(max(x0, 0), WN - 1);
    x1 = min(max(x1, 0), WN - 1);
    y0 = min(max(y0, 0), HN - 1);
    y1 = min(max(y1, 0), HN - 1);

    // replicate the main kernel's band test exactly (on clipped y0/y1)
    const int h0 = (h / R) * R;
    int lo = h0 - 3;
    lo = lo < 0 ? 0 : (lo > HN - BAND ? HN - BAND : lo);
    if ((y0 >= lo) && (y1 <= lo + BAND - 1)) return;   // clean: main kernel was exact

    const float x0f = (float)x0, x1f = (float)x1;
    const float y0f = (float)y0, y1f = (float)y1;
    const float wa = (x1f - x) * (y1f - y);
    const float wb = (x1f - x) * (y - y0f);
    const float wc = (x - x0f) * (y1f - y);
    const float wd = (x - x0f) * (y - y0f);

    const int offA = y0 * WN + x0;
    const int offB = y1 * WN + x0;
    const int offC = y0 * WN + x1;
    const int offD = y1 * WN + x1;

    const float* imgb = img + (size_t)b * CN * HW;
    float* outb = out + (size_t)b * CN * HW + hw;

#pragma unroll 8
    for (int c = 0; c < CN; ++c) {
        const float* p = imgb + (size_t)c * HW;
        outb[(size_t)c * HW] = wa * p[offA] + wb * p[offB] + wc * p[offC] + wd * p[offD];
    }
}

extern "C" void kernel_launch(void* const* d_in, const int* in_sizes, int n_in,
                              void* d_out, int out_size, void* d_ws, size_t ws_size,
                              hipStream_t stream) {
    const float* img = (const float*)d_in[0];
    const float* flo = (const float*)d_in[1];
    float* out = (float*)d_out;

    const int grid = BN * (HN / R) * CSPLIT;   // 1024 blocks
    warp_kernel<<<grid, TPB, 0, stream>>>(img, flo, out);

    const int total = BN * HW;
    fixup_kernel<<<(total + 255) / 256, 256, 0, stream>>>(img, flo, out);
}

// Round 9
// 126.589 us; speedup vs baseline: 1.0706x; 1.0706x over previous
//
#include <hip/hip_runtime.h>

// Bilinear backward warp: img [B,C,H,W] f32, flo [B,2,H,W] f32 -> out [B,C,H,W] f32
// B=8, C=64, H=256, W=448
//
// R9 = R3's proven-exact skeleton (2 LDS buffers, stage c+1 at top of round,
// one __syncthreads drain per channel, in-loop rare fallback) with ONE change:
// CSPLIT=4 -> grid 2048 -> 4 resident blocks/CU (28 waves, 87%) instead of 2.
// R3's 36% occupancy was grid-limited (512 blocks = 2/CU), not LDS-limited;
// all pipelining attempts (R4-R6) failed, but block-level TLP covers the
// per-round drain stalls for free.

#define BN 8
#define CN 64
#define HN 256
#define WN 448
#define HW (HN * WN)
#define R 4              // output rows per block
#define BAND 10          // staged img rows per channel (lo = h0-3)
#define TPB WN           // 448 threads = 7 waves
#define NXCD 8
#define CSPLIT 4
#define CLOOP (CN / CSPLIT)   // 16 channels per block

typedef __attribute__((address_space(1))) const void glb_v;
typedef __attribute__((address_space(3))) void lds_v;

__global__ __launch_bounds__(TPB) void warp_kernel(const float* __restrict__ img,
                                                   const float* __restrict__ flo,
                                                   float* __restrict__ out) {
    // 2 buffers x (4480+4) floats = 35872 B -> 4 blocks/CU
    __shared__ float lds[2][BAND * WN + 4];

    // XCD swizzle: 2048 blocks = 256/XCD = one batch per XCD; the 4
    // channel-quarters of a tile are adjacent wgids -> share L2 row bands.
    const int nwg = gridDim.x;            // 2048
    const int cpx = nwg / NXCD;           // 256
    const int bid = blockIdx.x;
    const int wgid = (bid % NXCD) * cpx + (bid / NXCD);

    const int b    = wgid / cpx;          // 0..7
    const int rem  = wgid % cpx;          // 0..255
    const int tile = rem >> 2;            // 0..63
    const int ch0  = (rem & 3) * CLOOP;   // 0,16,32,48
    const int h0   = tile * R;
    const int w    = threadIdx.x;         // 0..447

    int lo = h0 - 3;
    lo = lo < 0 ? 0 : (lo > HN - BAND ? HN - BAND : lo);

    const float* imgb = img + (size_t)b * CN * HW;
    const float* flob = flo + (size_t)b * 2 * HW;

    // ---- per-pixel setup, channel-invariant ----
    float wa[R], wb[R], wc[R], wd[R];
    int sA[R], sB[R];       // band-relative LDS word offsets
    int gA[R], gB[R];       // plane-relative global word offsets (fallback)
    int dx_[R];
    bool fb[R];
    bool anyfb = false;
#pragma unroll
    for (int r = 0; r < R; ++r) {
        const int h = h0 + r;
        const int hw = h * WN + w;
        const float fx = flob[hw];
        const float fy = flob[HW + hw];
        const float x = (float)w + fx;
        const float y = (float)h + fy;
        int x0 = (int)x;                 // trunc toward zero (matches ref)
        int x1 = x0 + 1;
        int y0 = (int)y;
        int y1 = y0 + 1;
        x0 = min(max(x0, 0), WN - 1);
        x1 = min(max(x1, 0), WN - 1);
        y0 = min(max(y0, 0), HN - 1);
        y1 = min(max(y1, 0), HN - 1);
        const float x0f = (float)x0, x1f = (float)x1;
        const float y0f = (float)y0, y1f = (float)y1;
        wa[r] = (x1f - x) * (y1f - y);
        wb[r] = (x1f - x) * (y - y0f);
        wc[r] = (x - x0f) * (y1f - y);
        wd[r] = (x - x0f) * (y - y0f);
        dx_[r] = x1 - x0;                // 0 only at l/r edge clip
        const bool inband = (y0 >= lo) && (y1 <= lo + BAND - 1);
        fb[r] = !inband;
        anyfb |= fb[r];
        const int rA = min(max(y0 - lo, 0), BAND - 1);
        const int rB = min(max(y1 - lo, 0), BAND - 1);
        sA[r] = rA * WN + x0;
        sB[r] = rB * WN + x0;
        gA[r] = y0 * WN + x0;
        gB[r] = y1 * WN + x0;
    }
    const bool dirty = __any(anyfb);    // wave-uniform, rare

    const int wave = threadIdx.x >> 6;   // 0..6
    const int lane = threadIdx.x & 63;

    // ---- staging: 10 rows x 448 = 4480 words = 17x1KB chunks + 2x256B tails ----
    auto stage = [&](int bufi, int c) {          // c = global channel
        const float* src = imgb + (size_t)c * HW + (size_t)lo * WN;
        float* dst = &lds[bufi][0];
        for (int s = wave; s < 17; s += 7) {
            __builtin_amdgcn_global_load_lds(
                (glb_v*)(src + s * 256 + lane * 4),
                (lds_v*)(dst + s * 256), 16, 0, 0);
        }
        if (wave < 2) {
            const int base = 17 * 256 + wave * 64;
            __builtin_amdgcn_global_load_lds(
                (glb_v*)(src + base + lane),
                (lds_v*)(dst + base), 4, 0, 0);
        }
    };

    stage(0, ch0);
    __syncthreads();

    float* outp = out + (size_t)b * CN * HW + (size_t)ch0 * HW + (size_t)h0 * WN + w;

    for (int cl = 0; cl < CLOOP; ++cl) {
        const int cur = cl & 1;
        if (cl + 1 < CLOOP) stage(cur ^ 1, ch0 + cl + 1);

        const float* buf = &lds[cur][0];
        float o[R];
        if (!dirty) {
#pragma unroll
            for (int r = 0; r < R; ++r) {
                const float a0 = buf[sA[r]];
                const float a1 = buf[sA[r] + 1];   // ds_read2_b32 pair
                const float b0 = buf[sB[r]];
                const float b1 = buf[sB[r] + 1];
                const float Ic = dx_[r] ? a1 : a0;
                const float Id = dx_[r] ? b1 : b0;
                o[r] = wa[r] * a0 + wb[r] * b0 + wc[r] * Ic + wd[r] * Id;
            }
        } else {
            const float* pg = imgb + (size_t)(ch0 + cl) * HW;
#pragma unroll
            for (int r = 0; r < R; ++r) {
                float a0 = buf[sA[r]];
                float a1 = buf[sA[r] + 1];
                float b0 = buf[sB[r]];
                float b1 = buf[sB[r] + 1];
                if (fb[r]) {
                    a0 = pg[gA[r]];
                    a1 = pg[gA[r] + dx_[r]];
                    b0 = pg[gB[r]];
                    b1 = pg[gB[r] + dx_[r]];
                }
                const float Ic = dx_[r] ? a1 : a0;
                const float Id = dx_[r] ? b1 : b0;
                o[r] = wa[r] * a0 + wb[r] * b0 + wc[r] * Ic + wd[r] * Id;
            }
        }
#pragma unroll
        for (int r = 0; r < R; ++r) {
            outp[(size_t)cl * HW + r * WN] = o[r];
        }
        __syncthreads();   // drain (stage cl+1 landed) + barrier, once per channel
    }
}

extern "C" void kernel_launch(void* const* d_in, const int* in_sizes, int n_in,
                              void* d_out, int out_size, void* d_ws, size_t ws_size,
                              hipStream_t stream) {
    const float* img = (const float*)d_in[0];
    const float* flo = (const float*)d_in[1];
    float* out = (float*)d_out;

    const int grid = BN * (HN / R) * CSPLIT;   // 2048 blocks
    warp_kernel<<<grid, TPB, 0, stream>>>(img, flo, out);
}

// Round 10
// 116.229 us; speedup vs baseline: 1.1660x; 1.0891x over previous
//
#include <hip/hip_runtime.h>

// Bilinear backward warp: img [B,C,H,W] f32, flo [B,2,H,W] f32 -> out [B,C,H,W] f32
// B=8, C=64, H=256, W=448
//
// R10: R7's winning skeleton (4 rotating LDS buffers, 2 channels per round,
// one __syncthreads drain per round, in-loop rare fallback) re-tiled to
// 256-thread blocks (4 waves) over 4x224 output tiles:
//  - every 448-thread config stuck at ~2 resident blocks (14 waves)/CU;
//    256-thread blocks reached 3.5+ (R6) -> target 4 resident = 16 waves.
//  - staged band is 10 rows x 232 cols: word stride 232 % 32 = 8, so
//    same-x different-row taps land on different banks (fixes the 1.1e7
//    SQ_LDS_BANK_CONFLICT of the stride-448 layout).

#define BN 8
#define CN 64
#define HN 256
#define WN 448
#define HW (HN * WN)
#define R 4               // output rows per block
#define BAND 10           // staged rows: lo = h0-3 .. h0+6
#define COLS 224          // output cols per block
#define LCOLS 232         // staged cols (halo >= 4 both sides)
#define BWORDS (BAND * LCOLS)   // 2320 words = 9280 B per buffer
#define TPB 256           // 4 waves
#define NXCD 8
#define CSPLIT 2
#define CLOOP (CN / CSPLIT)   // 32 channels per block
#define ROUNDS (CLOOP / 2)    // 16 rounds of 2 channels

typedef __attribute__((address_space(1))) const void glb_v;
typedef __attribute__((address_space(3))) void lds_v;

__global__ __launch_bounds__(TPB) void warp_kernel(const float* __restrict__ img,
                                                   const float* __restrict__ flo,
                                                   float* __restrict__ out) {
    // 4 x 2328 x 4 = 37248 B -> 4 blocks/CU
    __shared__ float lds[4][BWORDS + 8];

    // XCD swizzle: 2048 blocks = 256/XCD = one batch per XCD. Within a batch,
    // the 4 sub-blocks (2 col-tiles x 2 channel-halves) of a row-tile are
    // adjacent wgids -> share the same 10-row bands in L2.
    const int nwg = gridDim.x;            // 2048
    const int cpx = nwg / NXCD;           // 256
    const int bid = blockIdx.x;
    const int wgid = (bid % NXCD) * cpx + (bid / NXCD);

    const int b       = wgid / cpx;       // 0..7
    const int rem     = wgid % cpx;       // 0..255
    const int rowtile = rem >> 2;         // 0..63
    const int sub     = rem & 3;
    const int ct      = sub & 1;          // col tile: 0 or 1
    const int ch0     = (sub >> 1) * CLOOP;   // 0 or 32
    const int h0      = rowtile * R;
    const int c0      = ct * COLS;        // 0 or 224

    const int t    = threadIdx.x;         // 0..255 (224..255 idle in compute)
    const int wv   = t >> 6;              // 0..3
    const int lane = t & 63;

    int lo = h0 - 3;
    lo = lo < 0 ? 0 : (lo > HN - BAND ? HN - BAND : lo);
    int bc = c0 - 4;
    bc = bc < 0 ? 0 : (bc > WN - LCOLS ? WN - LCOLS : bc);

    const float* imgb = img + (size_t)b * CN * HW;
    const float* flob = flo + (size_t)b * 2 * HW;

    // ---- per-pixel setup, channel-invariant (threads >= COLS skip) ----
    float wa[R], wb[R], wc[R], wd[R];
    int sA[R], sB[R];       // band-relative LDS word offsets (clamped)
    int gA[R], gB[R];       // plane-relative global word offsets (fallback)
    int dx_[R];
    bool fb[R];
    bool anyfb = false;
    if (t < COLS) {
        const int w = c0 + t;
#pragma unroll
        for (int r = 0; r < R; ++r) {
            const int h = h0 + r;
            const int hw = h * WN + w;
            const float fx = flob[hw];
            const float fy = flob[HW + hw];
            const float x = (float)w + fx;
            const float y = (float)h + fy;
            int x0 = (int)x;                 // trunc toward zero (matches ref)
            int x1 = x0 + 1;
            int y0 = (int)y;
            int y1 = y0 + 1;
            x0 = min(max(x0, 0), WN - 1);
            x1 = min(max(x1, 0), WN - 1);
            y0 = min(max(y0, 0), HN - 1);
            y1 = min(max(y1, 0), HN - 1);
            const float x0f = (float)x0, x1f = (float)x1;
            const float y0f = (float)y0, y1f = (float)y1;
            wa[r] = (x1f - x) * (y1f - y);
            wb[r] = (x1f - x) * (y - y0f);
            wc[r] = (x - x0f) * (y1f - y);
            wd[r] = (x - x0f) * (y - y0f);
            dx_[r] = x1 - x0;                // 0 only at l/r edge clip
            const bool oky = (y0 >= lo) && (y1 <= lo + BAND - 1);
            const bool okx = (x0 >= bc) && (x1 <= bc + LCOLS - 1);
            fb[r] = !(oky && okx);
            anyfb |= fb[r];
            const int rA = min(max(y0 - lo, 0), BAND - 1);
            const int rB = min(max(y1 - lo, 0), BAND - 1);
            const int cx = min(max(x0 - bc, 0), LCOLS - 2);
            sA[r] = rA * LCOLS + cx;
            sB[r] = rB * LCOLS + cx;
            gA[r] = y0 * WN + x0;
            gB[r] = y1 * WN + x0;
        }
    }
    const bool dirty = __any(anyfb);    // wave-uniform, rare

    // ---- staging: 10 rows x 928 B; row r staged by wave r%4, lanes 0..57 ----
    auto stage = [&](int bufi, int c) {          // c = global channel
        const float* srcp = imgb + (size_t)c * HW + (size_t)lo * WN + bc;
        float* dstb = &lds[bufi][0];
        if (lane < 58) {
            for (int r = wv; r < BAND; r += 4) {
                __builtin_amdgcn_global_load_lds(
                    (glb_v*)(srcp + (size_t)r * WN + lane * 4),
                    (lds_v*)(dstb + r * LCOLS), 16, 0, 0);
            }
        }
    };

    stage(0, ch0 + 0);
    stage(1, ch0 + 1);
    __syncthreads();

    float* outp = out + (size_t)b * CN * HW + (size_t)ch0 * HW + (size_t)h0 * WN + c0 + t;

    for (int k = 0; k < ROUNDS; ++k) {
        const int m = 2 * k;
        if (k + 1 < ROUNDS) {
            stage((m + 2) & 3, ch0 + m + 2);
            stage((m + 3) & 3, ch0 + m + 3);
        }

        if (t < COLS) {
            const float* bufA = &lds[m & 3][0];
            const float* bufB = &lds[(m + 1) & 3][0];
            float oA[R], oB[R];
            if (!dirty) {
#pragma unroll
                for (int r = 0; r < R; ++r) {
                    const float Aa0 = bufA[sA[r]];
                    const float Aa1 = bufA[sA[r] + 1];   // ds_read2_b32 pair
                    const float Ab0 = bufA[sB[r]];
                    const float Ab1 = bufA[sB[r] + 1];
                    const float Ba0 = bufB[sA[r]];
                    const float Ba1 = bufB[sA[r] + 1];
                    const float Bb0 = bufB[sB[r]];
                    const float Bb1 = bufB[sB[r] + 1];
                    const float AIc = dx_[r] ? Aa1 : Aa0;
                    const float AId = dx_[r] ? Ab1 : Ab0;
                    const float BIc = dx_[r] ? Ba1 : Ba0;
                    const float BId = dx_[r] ? Bb1 : Bb0;
                    oA[r] = wa[r] * Aa0 + wb[r] * Ab0 + wc[r] * AIc + wd[r] * AId;
                    oB[r] = wa[r] * Ba0 + wb[r] * Bb0 + wc[r] * BIc + wd[r] * BId;
                }
            } else {
                const float* pgA = imgb + (size_t)(ch0 + m) * HW;
                const float* pgB = imgb + (size_t)(ch0 + m + 1) * HW;
#pragma unroll
                for (int r = 0; r < R; ++r) {
                    float Aa0 = bufA[sA[r]];
                    float Aa1 = bufA[sA[r] + 1];
                    float Ab0 = bufA[sB[r]];
                    float Ab1 = bufA[sB[r] + 1];
                    float Ba0 = bufB[sA[r]];
                    float Ba1 = bufB[sA[r] + 1];
                    float Bb0 = bufB[sB[r]];
                    float Bb1 = bufB[sB[r] + 1];
                    if (fb[r]) {
                        Aa0 = pgA[gA[r]];
                        Aa1 = pgA[gA[r] + dx_[r]];
                        Ab0 = pgA[gB[r]];
                        Ab1 = pgA[gB[r] + dx_[r]];
                        Ba0 = pgB[gA[r]];
                        Ba1 = pgB[gA[r] + dx_[r]];
                        Bb0 = pgB[gB[r]];
                        Bb1 = pgB[gB[r] + dx_[r]];
                    }
                    const float AIc = dx_[r] ? Aa1 : Aa0;
                    const float AId = dx_[r] ? Ab1 : Ab0;
                    const float BIc = dx_[r] ? Ba1 : Ba0;
                    const float BId = dx_[r] ? Bb1 : Bb0;
                    oA[r] = wa[r] * Aa0 + wb[r] * Ab0 + wc[r] * AIc + wd[r] * AId;
                    oB[r] = wa[r] * Ba0 + wb[r] * Bb0 + wc[r] * BIc + wd[r] * BId;
                }
            }
#pragma unroll
            for (int r = 0; r < R; ++r) {
                outp[(size_t)m * HW + r * WN] = oA[r];
                outp[(size_t)(m + 1) * HW + r * WN] = oB[r];
            }
        }
        __syncthreads();   // drain (stage k+1 landed) + barrier, once per round
    }
}

extern "C" void kernel_launch(void* const* d_in, const int* in_sizes, int n_in,
                              void* d_out, int out_size, void* d_ws, size_t ws_size,
                              hipStream_t stream) {
    const float* img = (const float*)d_in[0];
    const float* flo = (const float*)d_in[1];
    float* out = (float*)d_out;

    const int grid = BN * (HN / R) * (WN / COLS) * CSPLIT;   // 8*64*2*2 = 2048
    warp_kernel<<<grid, TPB, 0, stream>>>(img, flo, out);
}